// Round 5
// baseline (221.583 us; speedup 1.0000x reference)
//
#include <hip/hip_runtime.h>

#define EPS 1e-5f

typedef short v8s __attribute__((ext_vector_type(8)));
typedef float v4f __attribute__((ext_vector_type(4)));

__device__ inline unsigned short f2bf(float f) {
    union { float f; unsigned u; } v; v.f = f;
    unsigned r = v.u + 0x7FFFu + ((v.u >> 16) & 1u);
    return (unsigned short)(r >> 16);
}
__device__ inline unsigned pack2(float a, float b) {
    return (unsigned)f2bf(a) | ((unsigned)f2bf(b) << 16);
}
__device__ inline float bfu2f(unsigned hi16) {        // hi16 = bf16 in low 16 bits
    union { unsigned u; float f; } v; v.u = hi16 << 16; return v.f;
}

// LDS map (50,816 B total -> 3 blocks/CU):
//   [0      .. 25600)  QKf   float[64][100]   Q(rows r<4, pre-scaled by simA*log2e) + K fp32
//   [25600  .. 38912)  Vb    ushort[64][104]  V bf16 (B-operand rows)
//   [38912  .. 48896)  Pb    ushort[48][104]  P strip bf16 (A-operand rows)
//   [48896  .. 49280)  zbuf  float[96]        1/Z per row
//   [49280  .. 50816)  sbufb ushort[768]      per-group output staging (bf16)
//   phase-1 overlay: Xb ushort[96][72] @0, Wb ushort[128][72] @13824
template<bool DIRECT>
__global__ __launch_bounds__(256, 3) void attn_kernel(
    const float* __restrict__ x,
    const float* __restrict__ w,
    const float* __restrict__ qkv_gamma, const float* __restrict__ qkv_beta,
    const float* __restrict__ qkv_mean,  const float* __restrict__ qkv_var,
    const float* __restrict__ sim_gamma, const float* __restrict__ sim_beta,
    const float* __restrict__ sim_mean,  const float* __restrict__ sim_var,
    const float* __restrict__ out_gamma, const float* __restrict__ out_beta,
    const float* __restrict__ out_mean,  const float* __restrict__ out_var,
    void* __restrict__ dstv)
{
    __shared__ __align__(16) unsigned char smem[50816];
    float (*QKf)[100]         = (float(*)[100])smem;
    unsigned short (*Vb)[104] = (unsigned short(*)[104])(smem + 25600);
    unsigned short (*Pb)[104] = (unsigned short(*)[104])(smem + 38912);
    float* zbuf               = (float*)(smem + 48896);
    unsigned short* sbufb     = (unsigned short*)(smem + 49280);
    unsigned short (*Xb)[72]  = (unsigned short(*)[72])smem;
    unsigned short (*Wb)[72]  = (unsigned short(*)[72])(smem + 13824);

    const int tid  = threadIdx.x;
    const int lane = tid & 63;
    const int wid  = tid >> 6;
    const int quad = lane >> 4;
    const int b  = blockIdx.x;          // b = nt*64 + hs
    const int nt = b >> 6;
    const int hs = b & 63;

    const float* xb = x + (size_t)nt * 393216 + (size_t)hs * 64;
    const float4* x4 = reinterpret_cast<const float4*>(xb);
    const float4* w4 = reinterpret_cast<const float4*>(w);

    // ---------------- Phase 1a: stage X, W as bf16 ----------------
    #pragma unroll
    for (int it = 0; it < 6; ++it) {
        int idx = tid + it * 256;               // 1536 float4s
        int cl = idx >> 4, v = idx & 15;
        float4 val = x4[cl * 1024 + v];
        unsigned* dx = (unsigned*)&Xb[cl][v * 4];
        dx[0] = pack2(val.x, val.y);
        dx[1] = pack2(val.z, val.w);
    }
    #pragma unroll
    for (int it = 0; it < 8; ++it) {
        int idx = tid + it * 256;               // 2048 float4s
        int r = idx >> 4, v = idx & 15;
        float4 val = w4[r * 16 + v];
        unsigned* dw = (unsigned*)&Wb[r][v * 4];
        dw[0] = pack2(val.x, val.y);
        dw[1] = pack2(val.z, val.w);
    }
    __syncthreads();

    // ---------------- Phase 1b: QKV = W @ X via MFMA ----------------
    v4f acc[2][6];
    #pragma unroll
    for (int mi = 0; mi < 2; ++mi)
        #pragma unroll
        for (int ni = 0; ni < 6; ++ni) acc[mi][ni] = (v4f)(0.f);

    #pragma unroll
    for (int kt = 0; kt < 2; ++kt) {
        v8s a0 = *reinterpret_cast<const v8s*>(&Wb[(wid * 2 + 0) * 16 + (lane & 15)][kt * 32 + quad * 8]);
        v8s a1 = *reinterpret_cast<const v8s*>(&Wb[(wid * 2 + 1) * 16 + (lane & 15)][kt * 32 + quad * 8]);
        #pragma unroll
        for (int ni = 0; ni < 6; ++ni) {
            v8s bfr = *reinterpret_cast<const v8s*>(&Xb[ni * 16 + (lane & 15)][kt * 32 + quad * 8]);
            acc[0][ni] = __builtin_amdgcn_mfma_f32_16x16x32_bf16(a0, bfr, acc[0][ni], 0, 0, 0);
            acc[1][ni] = __builtin_amdgcn_mfma_f32_16x16x32_bf16(a1, bfr, acc[1][ni], 0, 0, 0);
        }
    }
    __syncthreads();    // staging dead; region becomes QKf

    // epilogue: BN; rows r<8 -> QKf fp32 (Q rows scaled by simA*log2e); r>=8 -> Vb bf16
    #pragma unroll
    for (int mi = 0; mi < 2; ++mi) {
        const int mt = wid * 2 + mi;            // = group g
        #pragma unroll
        for (int reg = 0; reg < 4; ++reg) {
            int o = mt * 16 + quad * 4 + reg;
            int r = o & 15;
            float sc = qkv_gamma[o] * rsqrtf(qkv_var[o] + EPS);
            float mb = qkv_beta[o] - qkv_mean[o] * sc;
            float sA = sim_gamma[mt] * rsqrtf(sim_var[mt] + EPS) * 1.44269504f; // fold log2e
            if (r < 4) { sc *= sA; mb *= sA; }
            if (r < 8) {
                #pragma unroll
                for (int ni = 0; ni < 6; ++ni)
                    QKf[mt * 8 + r][ni * 16 + (lane & 15)] = acc[mi][ni][reg] * sc + mb;
            } else {
                #pragma unroll
                for (int ni = 0; ni < 6; ++ni)
                    Vb[mt * 8 + (r - 8)][ni * 16 + (lane & 15)] = f2bf(acc[mi][ni][reg] * sc + mb);
            }
        }
    }
    __syncthreads();

    // ---------------- Phase 2: per-group attention ----------------
    const int ib = tid >> 3;    // 0..31 : rows i = ib*3 + ii
    const int jb = tid & 7;     // 0..7  : cols j = jb*12 + jj

    for (int g = 0; g < 8; ++g) {
        // ---- scores (fp32 VALU, K=4; Q pre-scaled; additive BN terms cancel) ----
        float q[4][3];
        #pragma unroll
        for (int c = 0; c < 4; ++c)
            #pragma unroll
            for (int ii = 0; ii < 3; ++ii)
                q[c][ii] = QKf[g * 8 + c][ib * 3 + ii];

        float sim[3][12];
        #pragma unroll
        for (int ii = 0; ii < 3; ++ii)
            #pragma unroll
            for (int jj = 0; jj < 12; ++jj) sim[ii][jj] = 0.f;

        #pragma unroll
        for (int c = 0; c < 4; ++c) {
            const float* kr = &QKf[g * 8 + 4 + c][jb * 12];
            v4f kA = *reinterpret_cast<const v4f*>(kr);
            v4f kB = *reinterpret_cast<const v4f*>(kr + 4);
            v4f kC = *reinterpret_cast<const v4f*>(kr + 8);
            #pragma unroll
            for (int ii = 0; ii < 3; ++ii) {
                float qq = q[c][ii];
                sim[ii][0] += qq * kA.x; sim[ii][1]  += qq * kA.y;
                sim[ii][2] += qq * kA.z; sim[ii][3]  += qq * kA.w;
                sim[ii][4] += qq * kB.x; sim[ii][5]  += qq * kB.y;
                sim[ii][6] += qq * kB.z; sim[ii][7]  += qq * kB.w;
                sim[ii][8] += qq * kC.x; sim[ii][9]  += qq * kC.y;
                sim[ii][10] += qq * kC.z; sim[ii][11] += qq * kC.w;
            }
        }

        float p[3] = {0.f, 0.f, 0.f};
        #pragma unroll
        for (int ii = 0; ii < 3; ++ii)
            #pragma unroll
            for (int jj = 0; jj < 12; ++jj) {
                float e = exp2f(sim[ii][jj]);       // log2e folded into Q scale
                sim[ii][jj] = e;
                p[ii] += e;
            }
        #pragma unroll
        for (int ii = 0; ii < 3; ++ii) {
            p[ii] += __shfl_xor(p[ii], 1);
            p[ii] += __shfl_xor(p[ii], 2);
            p[ii] += __shfl_xor(p[ii], 4);
        }
        if (jb == 0) {
            #pragma unroll
            for (int ii = 0; ii < 3; ++ii)
                zbuf[ib * 3 + ii] = __builtin_amdgcn_rcpf(p[ii]);
        }

        // ---- two i-strips: P -> LDS (bf16, unnormalized), PV via MFMA ----
        #pragma unroll
        for (int s = 0; s < 2; ++s) {
            if ((tid >> 7) == s) {              // waves owning rows of this strip
                int rb = (ib - s * 16) * 3;
                #pragma unroll
                for (int ii = 0; ii < 3; ++ii) {
                    uint2* pr = (uint2*)&Pb[rb + ii][jb * 12];
                    uint2 v0, v1;
                    v0.x = pack2(sim[ii][0], sim[ii][1]);
                    v0.y = pack2(sim[ii][2], sim[ii][3]);
                    v1.x = pack2(sim[ii][4], sim[ii][5]);
                    v1.y = pack2(sim[ii][6], sim[ii][7]);
                    pr[0] = v0;
                    pr[1] = v1;
                    ((unsigned*)pr)[4] = pack2(sim[ii][8], sim[ii][9]);
                    ((unsigned*)pr)[5] = pack2(sim[ii][10], sim[ii][11]);
                }
            }
            __syncthreads();

            if (wid < 3) {                      // wave = m-tile of the 48-row strip
                const int mt = wid;
                v4f pv = (v4f)(0.f);
                #pragma unroll
                for (int kt = 0; kt < 3; ++kt) {
                    v8s a = *reinterpret_cast<const v8s*>(&Pb[mt * 16 + (lane & 15)][kt * 32 + quad * 8]);
                    v8s bv = *reinterpret_cast<const v8s*>(&Vb[g * 8 + (lane & 7)][kt * 32 + quad * 8]);
                    pv = __builtin_amdgcn_mfma_f32_16x16x32_bf16(a, bv, pv, 0, 0, 0);
                }
                if ((lane & 15) < 8) {
                    int c = lane & 15;
                    int d = g * 8 + c;
                    float osc = out_gamma[d] * rsqrtf(out_var[d] + EPS);
                    float ob  = out_beta[d] - out_mean[d] * osc;
                    v4f z = *reinterpret_cast<const v4f*>(&zbuf[s * 48 + mt * 16 + quad * 4]);
                    float o0 = pv[0] * (z[0] * osc) + ob;
                    float o1 = pv[1] * (z[1] * osc) + ob;
                    float o2 = pv[2] * (z[2] * osc) + ob;
                    float o3 = pv[3] * (z[3] * osc) + ob;
                    // sbufb flat idx = c*96 + cl  (cl = s*48 + mt*16 + quad*4 + reg)
                    uint2 pk;
                    pk.x = pack2(o0, o1);
                    pk.y = pack2(o2, o3);
                    ((uint2*)sbufb)[c * 24 + s * 12 + mt * 4 + quad] = pk;
                }
            }
            __syncthreads();
        }

        // ---- store this group's 8x96 block (bf16) ----
        if (DIRECT) {
            float* dst = (float*)dstv;
            #pragma unroll
            for (int t = 0; t < 3; ++t) {
                int idx = tid * 3 + t;
                int dd = idx / 96, cl = idx - dd * 96;
                dst[(size_t)nt * 393216 + (size_t)cl * 4096 + (size_t)(g * 8 + dd) * 64 + hs]
                    = bfu2f(sbufb[dd * 96 + cl]);
            }
        } else {
            if (tid < 96) {
                uint4 vv = ((const uint4*)sbufb)[tid];
                reinterpret_cast<uint4*>(dstv)[(size_t)b * 768 + g * 96 + tid] = vv;
            }
        }
        __syncthreads();   // sbufb/zbuf reused next group
    }
}

// ws bf16 (nt, hs, d, cl) -> out fp32 (nt, cl, d, hs); block = (nt, d-pair)
__global__ __launch_bounds__(256) void transpose_kernel(const unsigned short* __restrict__ ws,
                                                        float* __restrict__ out)
{
    __shared__ float tile[2][64][97];
    const int blk = blockIdx.x;          // nt*32 + dp
    const int nt = blk >> 5, dp = blk & 31;
    const uint2* ws2 = reinterpret_cast<const uint2*>(ws);
    float4* out4 = reinterpret_cast<float4*>(out);

    for (int idx = threadIdx.x; idx < 3072; idx += 256) {
        int hsr = idx / 48, rem = idx - hsr * 48;
        int dd = rem / 24, c4 = rem - dd * 24;
        uint2 v = ws2[(size_t)(nt * 64 + hsr) * 1536 + (size_t)(dp * 2 + dd) * 24 + c4];
        tile[dd][hsr][c4 * 4 + 0] = bfu2f(v.x & 0xFFFFu);
        tile[dd][hsr][c4 * 4 + 1] = bfu2f(v.x >> 16);
        tile[dd][hsr][c4 * 4 + 2] = bfu2f(v.y & 0xFFFFu);
        tile[dd][hsr][c4 * 4 + 3] = bfu2f(v.y >> 16);
    }
    __syncthreads();

    for (int idx = threadIdx.x; idx < 3072; idx += 256) {
        int cl = idx >> 5, rem = idx & 31;
        int dd = rem >> 4, h4 = rem & 15;
        float4 v = make_float4(tile[dd][h4 * 4 + 0][cl], tile[dd][h4 * 4 + 1][cl],
                               tile[dd][h4 * 4 + 2][cl], tile[dd][h4 * 4 + 3][cl]);
        out4[(size_t)nt * 98304 + (size_t)cl * 1024 + (size_t)(dp * 2 + dd) * 16 + h4] = v;
    }
}

extern "C" void kernel_launch(void* const* d_in, const int* in_sizes, int n_in,
                              void* d_out, int out_size, void* d_ws, size_t ws_size,
                              hipStream_t stream) {
    const float* x         = (const float*)d_in[0];
    const float* w_qkv     = (const float*)d_in[1];
    const float* qkv_gamma = (const float*)d_in[2];
    const float* qkv_beta  = (const float*)d_in[3];
    const float* qkv_mean  = (const float*)d_in[4];
    const float* qkv_var   = (const float*)d_in[5];
    const float* sim_gamma = (const float*)d_in[6];
    const float* sim_beta  = (const float*)d_in[7];
    const float* sim_mean  = (const float*)d_in[8];
    const float* sim_var   = (const float*)d_in[9];
    const float* out_gamma = (const float*)d_in[10];
    const float* out_beta  = (const float*)d_in[11];
    const float* out_mean  = (const float*)d_in[12];
    const float* out_var   = (const float*)d_in[13];
    float* out = (float*)d_out;

    const size_t ws_need = (size_t)2048 * 6144 * sizeof(unsigned short);  // 25.2 MB

    if (ws_size >= ws_need) {
        unsigned short* wsb = (unsigned short*)d_ws;
        attn_kernel<false><<<2048, 256, 0, stream>>>(
            x, w_qkv, qkv_gamma, qkv_beta, qkv_mean, qkv_var,
            sim_gamma, sim_beta, sim_mean, sim_var,
            out_gamma, out_beta, out_mean, out_var, wsb);
        transpose_kernel<<<1024, 256, 0, stream>>>(wsb, out);
    } else {
        attn_kernel<true><<<2048, 256, 0, stream>>>(
            x, w_qkv, qkv_gamma, qkv_beta, qkv_mean, qkv_var,
            sim_gamma, sim_beta, sim_mean, sim_var,
            out_gamma, out_beta, out_mean, out_var, out);
    }
}